// Round 5
// baseline (2648.835 us; speedup 1.0000x reference)
//
#include <hip/hip_runtime.h>
#include <stdint.h>

#define DH 128
#define BCAP 1024   // edges per 32-node bucket (lambda=512; overflow P ~ 1e-80)

typedef __attribute__((ext_vector_type(8))) _Float16 half8;
typedef __attribute__((ext_vector_type(2))) _Float16 half2v;
typedef __attribute__((ext_vector_type(2))) __fp16 fp16x2;
typedef __attribute__((ext_vector_type(4))) float f32x4;

// ---------- K0: pack 6 weight matrices [128x128] f32 -> f16 MFMA B-frag layout
// layout index: ((mat*4 + kt)*8 + nt)*64*8 + lane*8 + j
// frag element j of lane: B[k = kt*32 + (lane>>4)*8 + j][n = nt*16 + (lane&15)]
__global__ __launch_bounds__(256) void pack_weights(
    const float* __restrict__ wz, const float* __restrict__ uz,
    const float* __restrict__ wr, const float* __restrict__ ur,
    const float* __restrict__ w,  const float* __restrict__ u,
    _Float16* __restrict__ wf) {
  int t = blockIdx.x * 256 + threadIdx.x;
  if (t >= 6 * 16384) return;
  int mat = t >> 14;
  int r = t & 16383;
  int j = r & 7;
  int lane = (r >> 3) & 63;
  int nt = (r >> 9) & 7;
  int kt = (r >> 12) & 3;
  int k = kt * 32 + ((lane >> 4) << 3) + j;
  int n = nt * 16 + (lane & 15);
  const float* m_;
  switch (mat) {
    case 0: m_ = wz; break; case 1: m_ = uz; break; case 2: m_ = wr; break;
    case 3: m_ = ur; break; case 4: m_ = w;  break; default: m_ = u;
  }
  wf[t] = (_Float16)m_[k * DH + n];
}

// ---------- bucket scatter: single pass, fixed-capacity buckets of 32 dst nodes
// record = (dst&31)<<17 | src   (src < 2^17)
__global__ __launch_bounds__(256) void scatter_bucket(
    const int* __restrict__ src, const int* __restrict__ dst,
    int* __restrict__ cursor, int* __restrict__ ebuf, int E) {
  int i = (blockIdx.x * 256 + threadIdx.x) * 4;
  if (i + 3 < E) {
    int4 d4 = *(const int4*)&dst[i];
    int4 s4 = *(const int4*)&src[i];
    int p0 = atomicAdd(&cursor[d4.x >> 5], 1);
    int p1 = atomicAdd(&cursor[d4.y >> 5], 1);
    int p2 = atomicAdd(&cursor[d4.z >> 5], 1);
    int p3 = atomicAdd(&cursor[d4.w >> 5], 1);
    if (p0 < BCAP) ebuf[((size_t)(d4.x >> 5) << 10) + p0] = ((d4.x & 31) << 17) | s4.x;
    if (p1 < BCAP) ebuf[((size_t)(d4.y >> 5) << 10) + p1] = ((d4.y & 31) << 17) | s4.y;
    if (p2 < BCAP) ebuf[((size_t)(d4.z >> 5) << 10) + p2] = ((d4.z & 31) << 17) | s4.z;
    if (p3 < BCAP) ebuf[((size_t)(d4.w >> 5) << 10) + p3] = ((d4.w & 31) << 17) | s4.w;
  } else {
    for (; i < E; ++i) {
      int d = dst[i], sv = src[i];
      int p = atomicAdd(&cursor[d >> 5], 1);
      if (p < BCAP) ebuf[((size_t)(d >> 5) << 10) + p] = ((d & 31) << 17) | sv;
    }
  }
}

// ---------- A-fragment loaders (f32 -> f16 packed convert) ----------
__device__ __forceinline__ half8 load_afrag(const float* __restrict__ base, int row, int ko) {
  const float* p = base + (size_t)row * DH + ko;
  float4 a = *(const float4*)p;
  float4 b = *(const float4*)(p + 4);
  union { half8 v; fp16x2 h[4]; } r;
  r.h[0] = __builtin_amdgcn_cvt_pkrtz(a.x, a.y);
  r.h[1] = __builtin_amdgcn_cvt_pkrtz(a.z, a.w);
  r.h[2] = __builtin_amdgcn_cvt_pkrtz(b.x, b.y);
  r.h[3] = __builtin_amdgcn_cvt_pkrtz(b.z, b.w);
  return r.v;
}
__device__ __forceinline__ half8 load_afrag_h(const _Float16* __restrict__ base,
                                              int row, int ko) {
  return *(const half8*)(base + (size_t)row * DH + ko);
}

// ---------- K1: m = sigmoid(f_dst@wr + h@ur + br) * h ----------
// Writes interleaved fp16 row hm[node]: 256 halves, pair p: [h_{2p}, h_{2p+1}, m_{2p}, m_{2p+1}]
__global__ __launch_bounds__(256) void k1_node_gate(
    const float* __restrict__ fdst, const float* __restrict__ h,
    const _Float16* __restrict__ wf, const float* __restrict__ br,
    _Float16* __restrict__ hm, int N) {
  const _Float16* wrf = wf + 2 * 16384;
  const _Float16* urf = wf + 3 * 16384;
  int lane = threadIdx.x & 63, wid = threadIdx.x >> 6;
  int rowb = blockIdx.x * 64 + wid * 16;
  int mrow = lane & 15, g = lane >> 4;
  int arow = rowb + mrow; if (arow > N - 1) arow = N - 1;
  f32x4 acc[8];
#pragma unroll
  for (int i = 0; i < 8; ++i) acc[i] = (f32x4){0.f, 0.f, 0.f, 0.f};
#pragma unroll
  for (int kh = 0; kh < 2; ++kh) {
    const float* srcm = kh ? h : fdst;
    const _Float16* bfm = kh ? urf : wrf;
#pragma unroll
    for (int kt = 0; kt < 4; ++kt) {
      half8 af = load_afrag(srcm, arow, kt * 32 + g * 8);
#pragma unroll
      for (int nt = 0; nt < 8; ++nt) {
        half8 bf = *(const half8*)&bfm[(kt * 8 + nt) * 512 + lane * 8];
        acc[nt] = __builtin_amdgcn_mfma_f32_16x16x32_f16(af, bf, acc[nt], 0, 0, 0);
      }
    }
  }
  int orow = rowb + g * 4;
#pragma unroll
  for (int nt = 0; nt < 8; ++nt) {
    int col = nt * 16 + mrow;
    float bias = br[col];
#pragma unroll
    for (int r = 0; r < 4; ++r) {
      int row = orow + r;
      if (row < N) {
        float hval = h[(size_t)row * DH + col];
        float arg = acc[nt][r] + bias;
        float gv = 1.f / (1.f + __expf(-arg));
        float mv = gv * hval;
        size_t base = (size_t)row * 256 + (size_t)((col >> 1) << 2) + (col & 1);
        hm[base] = (_Float16)hval;
        hm[base + 2] = (_Float16)mv;
      }
    }
  }
}

// ---------- K3b: bucket-accumulate. One WG per 32-node bucket.
// LDS f32 accumulation of s and m row-sums; coalesced writeout.
__global__ __launch_bounds__(256) void k3_bucket(
    const int* __restrict__ cursor, const int* __restrict__ ebuf,
    const _Float16* __restrict__ hm,
    float* __restrict__ s, _Float16* __restrict__ mrh, int N) {
  __shared__ float sacc[32][128];
  __shared__ float macc[32][128];
  int b = blockIdx.x;
  int t = threadIdx.x;
  int lane = t & 63, wid = t >> 6;
  f32x4 z4 = (f32x4){0.f, 0.f, 0.f, 0.f};
#pragma unroll
  for (int k = 0; k < 4; ++k) {
    ((f32x4*)&sacc[0][0])[t + k * 256] = z4;
    ((f32x4*)&macc[0][0])[t + k * 256] = z4;
  }
  __syncthreads();
  int ec = cursor[b]; if (ec > BCAP) ec = BCAP;
  size_t base = (size_t)b << 10;
  int c2 = lane * 2;
  int e = wid;
  for (; e + 4 < ec; e += 8) {
    int pkA = ebuf[base + e];
    int pkB = ebuf[base + e + 4];
    int srcA = pkA & 0x1FFFF, dlA = pkA >> 17;
    int srcB = pkB & 0x1FFFF, dlB = pkB >> 17;
    uint2 qA = *(const uint2*)(hm + (size_t)srcA * 256 + lane * 4);
    uint2 qB = *(const uint2*)(hm + (size_t)srcB * 256 + lane * 4);
    half2v hA = __builtin_bit_cast(half2v, qA.x), mA = __builtin_bit_cast(half2v, qA.y);
    half2v hB = __builtin_bit_cast(half2v, qB.x), mB = __builtin_bit_cast(half2v, qB.y);
    atomicAdd(&sacc[dlA][c2],     (float)hA[0]);
    atomicAdd(&sacc[dlA][c2 + 1], (float)hA[1]);
    atomicAdd(&macc[dlA][c2],     (float)mA[0]);
    atomicAdd(&macc[dlA][c2 + 1], (float)mA[1]);
    atomicAdd(&sacc[dlB][c2],     (float)hB[0]);
    atomicAdd(&sacc[dlB][c2 + 1], (float)hB[1]);
    atomicAdd(&macc[dlB][c2],     (float)mB[0]);
    atomicAdd(&macc[dlB][c2 + 1], (float)mB[1]);
  }
  for (; e < ec; e += 4) {
    int pk = ebuf[base + e];
    int srcn = pk & 0x1FFFF, dl = pk >> 17;
    uint2 q = *(const uint2*)(hm + (size_t)srcn * 256 + lane * 4);
    half2v hh = __builtin_bit_cast(half2v, q.x), mm = __builtin_bit_cast(half2v, q.y);
    atomicAdd(&sacc[dl][c2],     (float)hh[0]);
    atomicAdd(&sacc[dl][c2 + 1], (float)hh[1]);
    atomicAdd(&macc[dl][c2],     (float)mm[0]);
    atomicAdd(&macc[dl][c2 + 1], (float)mm[1]);
  }
  __syncthreads();
  for (int r = wid; r < 32; r += 4) {
    int row = b * 32 + r;
    if (row < N) {
      float2 sv; sv.x = sacc[r][c2]; sv.y = sacc[r][c2 + 1];
      *(float2*)&s[(size_t)row * DH + c2] = sv;
      fp16x2 mv = __builtin_amdgcn_cvt_pkrtz(macc[r][c2], macc[r][c2 + 1]);
      *(fp16x2*)&mrh[(size_t)row * DH + c2] = mv;
    }
  }
}

// ---------- K4: z/h_tilde GEMMs + gated update; reads s from d_out, overwrites with h_new
__global__ __launch_bounds__(256) void k4_update(
    const float* __restrict__ fsrc, const float* __restrict__ s,
    const _Float16* __restrict__ mrh, const _Float16* __restrict__ wf,
    const float* __restrict__ bz, const float* __restrict__ bb,
    float* __restrict__ out, int N) {
  const _Float16* wzf = wf + 0 * 16384;
  const _Float16* uzf = wf + 1 * 16384;
  const _Float16* wwf = wf + 4 * 16384;
  const _Float16* uuf = wf + 5 * 16384;
  int lane = threadIdx.x & 63, wid = threadIdx.x >> 6;
  int rowb = blockIdx.x * 64 + wid * 16;
  int mrow = lane & 15, g = lane >> 4;
  int arow = rowb + mrow; if (arow > N - 1) arow = N - 1;
  f32x4 az[8], ah[8];
#pragma unroll
  for (int i = 0; i < 8; ++i) {
    az[i] = (f32x4){0.f, 0.f, 0.f, 0.f};
    ah[i] = (f32x4){0.f, 0.f, 0.f, 0.f};
  }
  // phase 1: f_src contributes to both gates
#pragma unroll
  for (int kt = 0; kt < 4; ++kt) {
    half8 af = load_afrag(fsrc, arow, kt * 32 + g * 8);
#pragma unroll
    for (int nt = 0; nt < 8; ++nt) {
      half8 b0 = *(const half8*)&wzf[(kt * 8 + nt) * 512 + lane * 8];
      half8 b1 = *(const half8*)&wwf[(kt * 8 + nt) * 512 + lane * 8];
      az[nt] = __builtin_amdgcn_mfma_f32_16x16x32_f16(af, b0, az[nt], 0, 0, 0);
      ah[nt] = __builtin_amdgcn_mfma_f32_16x16x32_f16(af, b1, ah[nt], 0, 0, 0);
    }
  }
  // phase 2: s @ uz -> z gate
#pragma unroll
  for (int kt = 0; kt < 4; ++kt) {
    half8 af = load_afrag(s, arow, kt * 32 + g * 8);
#pragma unroll
    for (int nt = 0; nt < 8; ++nt) {
      half8 b0 = *(const half8*)&uzf[(kt * 8 + nt) * 512 + lane * 8];
      az[nt] = __builtin_amdgcn_mfma_f32_16x16x32_f16(af, b0, az[nt], 0, 0, 0);
    }
  }
  // phase 3: mrh @ u -> candidate (mrh fp16, direct frag load)
#pragma unroll
  for (int kt = 0; kt < 4; ++kt) {
    half8 af = load_afrag_h(mrh, arow, kt * 32 + g * 8);
#pragma unroll
    for (int nt = 0; nt < 8; ++nt) {
      half8 b1 = *(const half8*)&uuf[(kt * 8 + nt) * 512 + lane * 8];
      ah[nt] = __builtin_amdgcn_mfma_f32_16x16x32_f16(af, b1, ah[nt], 0, 0, 0);
    }
  }
  int orow = rowb + g * 4;
#pragma unroll
  for (int nt = 0; nt < 8; ++nt) {
    int col = nt * 16 + mrow;
    float bzc = bz[col], bbc = bb[col];
#pragma unroll
    for (int r = 0; r < 4; ++r) {
      int row = orow + r;
      if (row < N) {
        float zarg = az[nt][r] + bzc;
        float z = 1.f / (1.f + __expf(-zarg));
        float e2 = __expf(2.f * (ah[nt][r] + bbc));
        float th = (e2 - 1.f) / (e2 + 1.f);
        float sv = s[(size_t)row * DH + col];
        out[(size_t)row * DH + col] = (1.f - z) * sv + z * th;
      }
    }
  }
}

extern "C" void kernel_launch(void* const* d_in, const int* in_sizes, int n_in,
                              void* d_out, int out_size, void* d_ws, size_t ws_size,
                              hipStream_t stream) {
  const float* h    = (const float*)d_in[0];
  const float* fsrc = (const float*)d_in[1];
  const float* fdst = (const float*)d_in[2];
  const int*   src  = (const int*)d_in[3];
  const int*   dst  = (const int*)d_in[4];
  const float* wz   = (const float*)d_in[5];
  const float* uz   = (const float*)d_in[6];
  const float* bz   = (const float*)d_in[7];
  const float* wr   = (const float*)d_in[8];
  const float* ur   = (const float*)d_in[9];
  const float* br   = (const float*)d_in[10];
  const float* w    = (const float*)d_in[11];
  const float* u    = (const float*)d_in[12];
  const float* b    = (const float*)d_in[13];
  int N = in_sizes[0] / DH;
  int E = in_sizes[3];
  float* out = (float*)d_out;

  int nbuck = (N + 31) / 32;  // 3125 for N=100000

  char* ws = (char*)d_ws;
  size_t o = 0;
  auto take = [&](size_t bytes) {
    char* p = ws + o;
    o = (o + bytes + 255) & ~(size_t)255;
    return p;
  };
  _Float16* wf     = (_Float16*)take(6 * 16384 * sizeof(_Float16));
  _Float16* hm     = (_Float16*)take((size_t)N * 256 * 2);  // interleaved h16|m16
  _Float16* mrh    = (_Float16*)take((size_t)N * DH * 2);
  int*      cursor = (int*)take((size_t)nbuck * 4);
  int*      ebuf   = (int*)take((size_t)nbuck * BCAP * 4);

  pack_weights<<<(6 * 16384 + 255) / 256, 256, 0, stream>>>(wz, uz, wr, ur, w, u, wf);
  (void)hipMemsetAsync(cursor, 0, (size_t)nbuck * 4, stream);
  scatter_bucket<<<((E + 3) / 4 + 255) / 256, 256, 0, stream>>>(src, dst, cursor, ebuf, E);
  k1_node_gate<<<(N + 63) / 64, 256, 0, stream>>>(fdst, h, wf, br, hm, N);
  k3_bucket<<<nbuck, 256, 0, stream>>>(cursor, ebuf, hm, out, mrh, N);
  k4_update<<<(N + 63) / 64, 256, 0, stream>>>(fsrc, out, mrh, wf, bz, b, out, N);
}

// Round 6
// 596.682 us; speedup vs baseline: 4.4393x; 4.4393x over previous
//
#include <hip/hip_runtime.h>
#include <stdint.h>

#define DH 128
#define BCAP 1024   // edges per 32-node bucket (lambda=512; overflow P ~ 1e-80)

typedef __attribute__((ext_vector_type(8))) _Float16 half8;
typedef __attribute__((ext_vector_type(2))) _Float16 half2v;
typedef __attribute__((ext_vector_type(2))) __fp16 fp16x2;
typedef __attribute__((ext_vector_type(4))) float f32x4;

// ---------- K0: pack 6 weight matrices [128x128] f32 -> f16 MFMA B-frag layout
__global__ __launch_bounds__(256) void pack_weights(
    const float* __restrict__ wz, const float* __restrict__ uz,
    const float* __restrict__ wr, const float* __restrict__ ur,
    const float* __restrict__ w,  const float* __restrict__ u,
    _Float16* __restrict__ wf) {
  int t = blockIdx.x * 256 + threadIdx.x;
  if (t >= 6 * 16384) return;
  int mat = t >> 14;
  int r = t & 16383;
  int j = r & 7;
  int lane = (r >> 3) & 63;
  int nt = (r >> 9) & 7;
  int kt = (r >> 12) & 3;
  int k = kt * 32 + ((lane >> 4) << 3) + j;
  int n = nt * 16 + (lane & 15);
  const float* m_;
  switch (mat) {
    case 0: m_ = wz; break; case 1: m_ = uz; break; case 2: m_ = wr; break;
    case 3: m_ = ur; break; case 4: m_ = w;  break; default: m_ = u;
  }
  wf[t] = (_Float16)m_[k * DH + n];
}

// ---------- bucket scatter: single pass, fixed-capacity buckets of 32 dst nodes
// record = (dst&31)<<17 | src   (src < 2^17)
__global__ __launch_bounds__(256) void scatter_bucket(
    const int* __restrict__ src, const int* __restrict__ dst,
    int* __restrict__ cursor, int* __restrict__ ebuf, int E) {
  int i = (blockIdx.x * 256 + threadIdx.x) * 4;
  if (i + 3 < E) {
    int4 d4 = *(const int4*)&dst[i];
    int4 s4 = *(const int4*)&src[i];
    int p0 = atomicAdd(&cursor[d4.x >> 5], 1);
    int p1 = atomicAdd(&cursor[d4.y >> 5], 1);
    int p2 = atomicAdd(&cursor[d4.z >> 5], 1);
    int p3 = atomicAdd(&cursor[d4.w >> 5], 1);
    if (p0 < BCAP) ebuf[((size_t)(d4.x >> 5) << 10) + p0] = ((d4.x & 31) << 17) | s4.x;
    if (p1 < BCAP) ebuf[((size_t)(d4.y >> 5) << 10) + p1] = ((d4.y & 31) << 17) | s4.y;
    if (p2 < BCAP) ebuf[((size_t)(d4.z >> 5) << 10) + p2] = ((d4.z & 31) << 17) | s4.z;
    if (p3 < BCAP) ebuf[((size_t)(d4.w >> 5) << 10) + p3] = ((d4.w & 31) << 17) | s4.w;
  } else {
    for (; i < E; ++i) {
      int d = dst[i], sv = src[i];
      int p = atomicAdd(&cursor[d >> 5], 1);
      if (p < BCAP) ebuf[((size_t)(d >> 5) << 10) + p] = ((d & 31) << 17) | sv;
    }
  }
}

// ---------- A-fragment loaders (f32 -> f16 packed convert) ----------
__device__ __forceinline__ half8 load_afrag(const float* __restrict__ base, int row, int ko) {
  const float* p = base + (size_t)row * DH + ko;
  float4 a = *(const float4*)p;
  float4 b = *(const float4*)(p + 4);
  union { half8 v; fp16x2 h[4]; } r;
  r.h[0] = __builtin_amdgcn_cvt_pkrtz(a.x, a.y);
  r.h[1] = __builtin_amdgcn_cvt_pkrtz(a.z, a.w);
  r.h[2] = __builtin_amdgcn_cvt_pkrtz(b.x, b.y);
  r.h[3] = __builtin_amdgcn_cvt_pkrtz(b.z, b.w);
  return r.v;
}
__device__ __forceinline__ half8 load_afrag_h(const _Float16* __restrict__ base,
                                              int row, int ko) {
  return *(const half8*)(base + (size_t)row * DH + ko);
}

// ---------- K1: m = sigmoid(f_dst@wr + h@ur + br) * h ----------
// Writes interleaved fp16 row hm[node]: 256 halves, pair p: [h_{2p}, h_{2p+1}, m_{2p}, m_{2p+1}]
__global__ __launch_bounds__(256) void k1_node_gate(
    const float* __restrict__ fdst, const float* __restrict__ h,
    const _Float16* __restrict__ wf, const float* __restrict__ br,
    _Float16* __restrict__ hm, int N) {
  const _Float16* wrf = wf + 2 * 16384;
  const _Float16* urf = wf + 3 * 16384;
  int lane = threadIdx.x & 63, wid = threadIdx.x >> 6;
  int rowb = blockIdx.x * 64 + wid * 16;
  int mrow = lane & 15, g = lane >> 4;
  int arow = rowb + mrow; if (arow > N - 1) arow = N - 1;
  f32x4 acc[8];
#pragma unroll
  for (int i = 0; i < 8; ++i) acc[i] = (f32x4){0.f, 0.f, 0.f, 0.f};
#pragma unroll
  for (int kh = 0; kh < 2; ++kh) {
    const float* srcm = kh ? h : fdst;
    const _Float16* bfm = kh ? urf : wrf;
#pragma unroll
    for (int kt = 0; kt < 4; ++kt) {
      half8 af = load_afrag(srcm, arow, kt * 32 + g * 8);
#pragma unroll
      for (int nt = 0; nt < 8; ++nt) {
        half8 bf = *(const half8*)&bfm[(kt * 8 + nt) * 512 + lane * 8];
        acc[nt] = __builtin_amdgcn_mfma_f32_16x16x32_f16(af, bf, acc[nt], 0, 0, 0);
      }
    }
  }
  int orow = rowb + g * 4;
#pragma unroll
  for (int nt = 0; nt < 8; ++nt) {
    int col = nt * 16 + mrow;
    float bias = br[col];
#pragma unroll
    for (int r = 0; r < 4; ++r) {
      int row = orow + r;
      if (row < N) {
        float hval = h[(size_t)row * DH + col];
        float arg = acc[nt][r] + bias;
        float gv = 1.f / (1.f + __expf(-arg));
        float mv = gv * hval;
        size_t base = (size_t)row * 256 + (size_t)((col >> 1) << 2) + (col & 1);
        hm[base] = (_Float16)hval;
        hm[base + 2] = (_Float16)mv;
      }
    }
  }
}

// ---------- K3b: bucket-sort in LDS (counting sort, int atomics only) then
// per-node register-accumulate gather (round-4 proven pattern).
__global__ __launch_bounds__(256) void k3_bucket(
    const int* __restrict__ cursor, const int* __restrict__ ebuf,
    const _Float16* __restrict__ hm,
    float* __restrict__ s, _Float16* __restrict__ mrh, int N) {
  __shared__ int cnt[32];
  __shared__ int off[33];
  __shared__ int slot[32];
  __shared__ int esrt[BCAP];
  int b = blockIdx.x, t = threadIdx.x;
  if (t < 32) cnt[t] = 0;
  __syncthreads();
  int ec = cursor[b]; if (ec > BCAP) ec = BCAP;
  size_t base = (size_t)b << 10;
  for (int i = t; i < ec; i += 256) {
    int pk = ebuf[base + i];
    atomicAdd(&cnt[pk >> 17], 1);
  }
  __syncthreads();
  if (t == 0) {
    int a = 0;
#pragma unroll
    for (int r = 0; r < 32; ++r) { off[r] = a; slot[r] = a; a += cnt[r]; }
    off[32] = a;
  }
  __syncthreads();
  for (int i = t; i < ec; i += 256) {
    int pk = ebuf[base + i];
    int dl = pk >> 17;
    int p = atomicAdd(&slot[dl], 1);
    esrt[p] = pk & 0x1FFFF;
  }
  __syncthreads();
  int lane = t & 63, wid = t >> 6;
  int c2 = lane * 2;
  for (int r = wid; r < 32; r += 4) {
    int row = b * 32 + r;
    if (row >= N) break;
    int e0 = off[r], e1 = off[r + 1];
    float sx = 0.f, sy = 0.f;
    half2v msum = (half2v)(_Float16)0.f;
    int e = e0;
    for (; e + 3 < e1; e += 4) {
      int u0 = esrt[e], u1 = esrt[e + 1], u2 = esrt[e + 2], u3 = esrt[e + 3];
      uint2 q0 = *(const uint2*)(hm + (size_t)u0 * 256 + lane * 4);
      uint2 q1 = *(const uint2*)(hm + (size_t)u1 * 256 + lane * 4);
      uint2 q2 = *(const uint2*)(hm + (size_t)u2 * 256 + lane * 4);
      uint2 q3 = *(const uint2*)(hm + (size_t)u3 * 256 + lane * 4);
      half2v h0 = __builtin_bit_cast(half2v, q0.x), m0 = __builtin_bit_cast(half2v, q0.y);
      half2v h1 = __builtin_bit_cast(half2v, q1.x), m1 = __builtin_bit_cast(half2v, q1.y);
      half2v h2 = __builtin_bit_cast(half2v, q2.x), m2 = __builtin_bit_cast(half2v, q2.y);
      half2v h3 = __builtin_bit_cast(half2v, q3.x), m3 = __builtin_bit_cast(half2v, q3.y);
      sx += ((float)h0[0] + (float)h1[0]) + ((float)h2[0] + (float)h3[0]);
      sy += ((float)h0[1] + (float)h1[1]) + ((float)h2[1] + (float)h3[1]);
      msum = msum + (m0 + m1) + (m2 + m3);
    }
    for (; e < e1; ++e) {
      int u0 = esrt[e];
      uint2 q0 = *(const uint2*)(hm + (size_t)u0 * 256 + lane * 4);
      half2v h0 = __builtin_bit_cast(half2v, q0.x), m0 = __builtin_bit_cast(half2v, q0.y);
      sx += (float)h0[0];
      sy += (float)h0[1];
      msum = msum + m0;
    }
    float2 so; so.x = sx; so.y = sy;
    *(float2*)&s[(size_t)row * DH + c2] = so;
    *(half2v*)&mrh[(size_t)row * DH + c2] = msum;
  }
}

// ---------- K4: z/h_tilde GEMMs + gated update; reads s from d_out, overwrites with h_new
__global__ __launch_bounds__(256) void k4_update(
    const float* __restrict__ fsrc, const float* __restrict__ s,
    const _Float16* __restrict__ mrh, const _Float16* __restrict__ wf,
    const float* __restrict__ bz, const float* __restrict__ bb,
    float* __restrict__ out, int N) {
  const _Float16* wzf = wf + 0 * 16384;
  const _Float16* uzf = wf + 1 * 16384;
  const _Float16* wwf = wf + 4 * 16384;
  const _Float16* uuf = wf + 5 * 16384;
  int lane = threadIdx.x & 63, wid = threadIdx.x >> 6;
  int rowb = blockIdx.x * 64 + wid * 16;
  int mrow = lane & 15, g = lane >> 4;
  int arow = rowb + mrow; if (arow > N - 1) arow = N - 1;
  f32x4 az[8], ah[8];
#pragma unroll
  for (int i = 0; i < 8; ++i) {
    az[i] = (f32x4){0.f, 0.f, 0.f, 0.f};
    ah[i] = (f32x4){0.f, 0.f, 0.f, 0.f};
  }
  // phase 1: f_src contributes to both gates
#pragma unroll
  for (int kt = 0; kt < 4; ++kt) {
    half8 af = load_afrag(fsrc, arow, kt * 32 + g * 8);
#pragma unroll
    for (int nt = 0; nt < 8; ++nt) {
      half8 b0 = *(const half8*)&wzf[(kt * 8 + nt) * 512 + lane * 8];
      half8 b1 = *(const half8*)&wwf[(kt * 8 + nt) * 512 + lane * 8];
      az[nt] = __builtin_amdgcn_mfma_f32_16x16x32_f16(af, b0, az[nt], 0, 0, 0);
      ah[nt] = __builtin_amdgcn_mfma_f32_16x16x32_f16(af, b1, ah[nt], 0, 0, 0);
    }
  }
  // phase 2: s @ uz -> z gate
#pragma unroll
  for (int kt = 0; kt < 4; ++kt) {
    half8 af = load_afrag(s, arow, kt * 32 + g * 8);
#pragma unroll
    for (int nt = 0; nt < 8; ++nt) {
      half8 b0 = *(const half8*)&uzf[(kt * 8 + nt) * 512 + lane * 8];
      az[nt] = __builtin_amdgcn_mfma_f32_16x16x32_f16(af, b0, az[nt], 0, 0, 0);
    }
  }
  // phase 3: mrh @ u -> candidate (mrh fp16, direct frag load)
#pragma unroll
  for (int kt = 0; kt < 4; ++kt) {
    half8 af = load_afrag_h(mrh, arow, kt * 32 + g * 8);
#pragma unroll
    for (int nt = 0; nt < 8; ++nt) {
      half8 b1 = *(const half8*)&uuf[(kt * 8 + nt) * 512 + lane * 8];
      ah[nt] = __builtin_amdgcn_mfma_f32_16x16x32_f16(af, b1, ah[nt], 0, 0, 0);
    }
  }
  int orow = rowb + g * 4;
#pragma unroll
  for (int nt = 0; nt < 8; ++nt) {
    int col = nt * 16 + mrow;
    float bzc = bz[col], bbc = bb[col];
#pragma unroll
    for (int r = 0; r < 4; ++r) {
      int row = orow + r;
      if (row < N) {
        float zarg = az[nt][r] + bzc;
        float z = 1.f / (1.f + __expf(-zarg));
        float e2 = __expf(2.f * (ah[nt][r] + bbc));
        float th = (e2 - 1.f) / (e2 + 1.f);
        float sv = s[(size_t)row * DH + col];
        out[(size_t)row * DH + col] = (1.f - z) * sv + z * th;
      }
    }
  }
}

extern "C" void kernel_launch(void* const* d_in, const int* in_sizes, int n_in,
                              void* d_out, int out_size, void* d_ws, size_t ws_size,
                              hipStream_t stream) {
  const float* h    = (const float*)d_in[0];
  const float* fsrc = (const float*)d_in[1];
  const float* fdst = (const float*)d_in[2];
  const int*   src  = (const int*)d_in[3];
  const int*   dst  = (const int*)d_in[4];
  const float* wz   = (const float*)d_in[5];
  const float* uz   = (const float*)d_in[6];
  const float* bz   = (const float*)d_in[7];
  const float* wr   = (const float*)d_in[8];
  const float* ur   = (const float*)d_in[9];
  const float* br   = (const float*)d_in[10];
  const float* w    = (const float*)d_in[11];
  const float* u    = (const float*)d_in[12];
  const float* b    = (const float*)d_in[13];
  int N = in_sizes[0] / DH;
  int E = in_sizes[3];
  float* out = (float*)d_out;

  int nbuck = (N + 31) / 32;  // 3125 for N=100000

  char* ws = (char*)d_ws;
  size_t o = 0;
  auto take = [&](size_t bytes) {
    char* p = ws + o;
    o = (o + bytes + 255) & ~(size_t)255;
    return p;
  };
  _Float16* wf     = (_Float16*)take(6 * 16384 * sizeof(_Float16));
  _Float16* hm     = (_Float16*)take((size_t)N * 256 * 2);  // interleaved h16|m16
  _Float16* mrh    = (_Float16*)take((size_t)N * DH * 2);
  int*      cursor = (int*)take((size_t)nbuck * 4);
  int*      ebuf   = (int*)take((size_t)nbuck * BCAP * 4);

  pack_weights<<<(6 * 16384 + 255) / 256, 256, 0, stream>>>(wz, uz, wr, ur, w, u, wf);
  (void)hipMemsetAsync(cursor, 0, (size_t)nbuck * 4, stream);
  scatter_bucket<<<((E + 3) / 4 + 255) / 256, 256, 0, stream>>>(src, dst, cursor, ebuf, E);
  k1_node_gate<<<(N + 63) / 64, 256, 0, stream>>>(fdst, h, wf, br, hm, N);
  k3_bucket<<<nbuck, 256, 0, stream>>>(cursor, ebuf, hm, out, mrh, N);
  k4_update<<<(N + 63) / 64, 256, 0, stream>>>(fsrc, out, mrh, wf, bz, b, out, N);
}